// Round 12
// baseline (48.315 us; speedup 1.0000x reference)
//
#include <hip/hip_runtime.h>

#define BATCH 2048
#define NTEACH 64

typedef __attribute__((ext_vector_type(8))) short short8;
typedef __attribute__((ext_vector_type(4))) float f32x4;

__device__ __forceinline__ unsigned short f2bf(float f) {
    unsigned u = __float_as_uint(f);
    u += 0x7FFFu + ((u >> 16) & 1u);          // round-to-nearest-even
    return (unsigned short)(u >> 16);
}

__device__ __forceinline__ short8 cvt8(float4 a, float4 b) {
    short8 r;
    r[0] = (short)f2bf(a.x); r[1] = (short)f2bf(a.y);
    r[2] = (short)f2bf(a.z); r[3] = (short)f2bf(a.w);
    r[4] = (short)f2bf(b.x); r[5] = (short)f2bf(b.y);
    r[6] = (short)f2bf(b.z); r[7] = (short)f2bf(b.w);
    return r;
}

// Barrier-free per-wave scan (R8-proven): each wave independently computes the
// stable ranking of teacher-t samples. Returns (start, count), wave-uniform.
// Works for any block size (uses lane id only; ord writes redundant, benign).
__device__ __forceinline__ int2 wave_scan(const int* __restrict__ tidx,
                                          int t, int* ord) {
    const int lane = threadIdx.x & 63;
    int base = 0, lt = 0;
#pragma unroll
    for (int r = 0; r < 32; ++r) {
        int i = r * 64 + lane;
        int v = tidx[i];
        bool f = (v == t);
        lt += (v < t) ? 1 : 0;
        unsigned long long b = __ballot(f);
        if (ord && f) {
            int rank = base + __builtin_popcountll(b & ((1ull << lane) - 1ull));
            ord[rank] = i;
        }
        base += __builtin_popcountll(b);
    }
#pragma unroll
    for (int off = 32; off; off >>= 1) lt += __shfl_down(lt, off);
    lt = __shfl(lt, 0);
    return make_int2(lt, base);
}

// ---------- K1: fused L0+L1. obs(48) -> h0(512, LDS only) -> h1(256) --------
// grid (8,64), 512 thr = 8 waves. Per 16-row chunk:
//   phase A: wave w computes h0[16][w*64 .. w*64+64) into swizzled LDS
//            (w0 B-frags hoisted: 4 subtiles x 2 ktiles, 8 MFMA)
//   phase B: wave = (cg = w>>2 of 2 col16-groups, kq = w&3 K-quarter):
//            h1 cols n0+cg*16, K 512 split 4 ways, LDS reduce, elu, store.
// h0 NEVER touches global memory. w0 read 8x (50 MB, L2/L3), w2 read once.
// MFMA 16x16x32 bf16 (verified R2-R10): A row=lane&15, k=(lane>>4)*8+j;
// B col=lane&15; D col=lane&15, row=(lane>>4)*4+j.
__global__ __launch_bounds__(512, 4) void k01_kernel(
    const float* __restrict__ obs, const int* __restrict__ tidx,
    const float* __restrict__ w0, const float* __restrict__ b0,
    const float* __restrict__ w2, const float* __restrict__ b2,
    int* __restrict__ offsets_g, int* __restrict__ order_g,
    unsigned short* __restrict__ h1) {
    __shared__ int ord[BATCH];                    // 8 KB
    __shared__ char h0s[16384];                   // 16 x 512 bf16, stride 1024B, XOR-swizzled
    __shared__ f32x4 red[2][3][64];               // 6 KB

    const int t = blockIdx.y;
    const int tid = threadIdx.x;
    const int lane = tid & 63, wid = tid >> 6;
    const int ln = lane & 15, kg = lane >> 4;
    const int a0 = wid * 64;                      // phase-A col base
    const int cg = wid >> 2, kq = wid & 3;        // phase-B roles
    const int n0 = blockIdx.x * 32;               // block h1 cols [n0, n0+32)

    // ---- issue w0 slice loads first (latency hidden under scan) ----
    float4 wa[4][2], wb[4][2];
#pragma unroll
    for (int nt = 0; nt < 4; ++nt) {
        const float* wr = w0 + ((size_t)t * 512 + a0 + nt * 16 + ln) * 48;
#pragma unroll
        for (int kt = 0; kt < 2; ++kt) {
            int kb = kt * 32 + kg * 8;
            const float* p = wr + (kb < 48 ? kb : 0);
            wa[nt][kt] = *(const float4*)p;
            wb[nt][kt] = *(const float4*)(p + 4);
        }
    }
    float biasA[4];
#pragma unroll
    for (int nt = 0; nt < 4; ++nt)
        biasA[nt] = b0[(size_t)t * 512 + a0 + nt * 16 + ln];

    // ---- scan while w0 loads are in flight ----
    int2 sc = wave_scan(tidx, t, ord);
    const int start = sc.x, count = sc.y;

    // ---- convert w0 (frees staged fp32 regs), then load+convert w2 slice ----
    short8 bf0[4][2];
#pragma unroll
    for (int nt = 0; nt < 4; ++nt)
#pragma unroll
        for (int kt = 0; kt < 2; ++kt) {
            short8 z = {0, 0, 0, 0, 0, 0, 0, 0};
            bf0[nt][kt] = (kt * 32 + kg * 8 < 48) ? cvt8(wa[nt][kt], wb[nt][kt]) : z;
        }
    const float* wr2 = w2 + ((size_t)t * 256 + n0 + cg * 16 + ln) * 512 + kq * 128;
    float4 w2a[4], w2b[4];
#pragma unroll
    for (int k4 = 0; k4 < 4; ++k4) {
        int kb = k4 * 32 + kg * 8;
        w2a[k4] = *(const float4*)(wr2 + kb);
        w2b[k4] = *(const float4*)(wr2 + kb + 4);
    }
    const float biasB = b2[(size_t)t * 256 + n0 + cg * 16 + ln];

    // ---- publish offsets/order for the l2f kernel ----
    if (blockIdx.x == 0) {
        if (tid == 0) {
            offsets_g[t] = start;
            if (t == 0) offsets_g[NTEACH] = BATCH;
        }
        for (int i = tid; i < count; i += 512) order_g[start + i] = ord[i];
    }
    if (count == 0) return;

    short8 bf1[4];
#pragma unroll
    for (int k4 = 0; k4 < 4; ++k4) bf1[k4] = cvt8(w2a[k4], w2b[k4]);

    for (int c0 = 0; c0 < count; c0 += 16) {
        __syncthreads();                  // h0s/red free from previous chunk
        // ---------- phase A: h0 chunk into LDS ----------
        {
            int lr = c0 + ln;
            const float* xr = obs + (size_t)ord[lr < count ? lr : 0] * 48;
            short8 af[2];
#pragma unroll
            for (int kt = 0; kt < 2; ++kt) {
                int kb = kt * 32 + kg * 8;
                short8 f8 = {0, 0, 0, 0, 0, 0, 0, 0};
                if (kb < 48)
                    f8 = cvt8(*(const float4*)(xr + kb), *(const float4*)(xr + kb + 4));
                af[kt] = f8;
            }
#pragma unroll
            for (int nt = 0; nt < 4; ++nt) {
                f32x4 acc = {0.f, 0.f, 0.f, 0.f};
                acc = __builtin_amdgcn_mfma_f32_16x16x32_bf16(af[0], bf0[nt][0], acc, 0, 0, 0);
                acc = __builtin_amdgcn_mfma_f32_16x16x32_bf16(af[1], bf0[nt][1], acc, 0, 0, 0);
                int col = a0 + nt * 16 + ln;
#pragma unroll
                for (int j = 0; j < 4; ++j) {
                    int row = kg * 4 + j;
                    float v = acc[j] + biasA[nt];
                    v = v > 0.f ? v : expm1f(v);
                    int byte = (row * 1024 + col * 2) ^ ((row & 7) << 4);
                    *(unsigned short*)(h0s + byte) = f2bf(v);
                }
            }
        }
        __syncthreads();                  // h0 chunk visible
        // ---------- phase B: h1 cols n0+cg*16, K-quarter kq ----------
        f32x4 acc = {0.f, 0.f, 0.f, 0.f};
#pragma unroll
        for (int k4 = 0; k4 < 4; ++k4) {
            int colk = kq * 128 + k4 * 32 + kg * 8;
            int byte = (ln * 1024 + colk * 2) ^ ((ln & 7) << 4);
            acc = __builtin_amdgcn_mfma_f32_16x16x32_bf16(
                *(const short8*)(h0s + byte), bf1[k4], acc, 0, 0, 0);
        }
        if (kq > 0) red[cg][kq - 1][lane] = acc;
        __syncthreads();
        if (kq == 0) {
#pragma unroll
            for (int s = 0; s < 3; ++s) {
                f32x4 r = red[cg][s][lane];
                acc[0] += r[0]; acc[1] += r[1]; acc[2] += r[2]; acc[3] += r[3];
            }
#pragma unroll
            for (int j = 0; j < 4; ++j) {
                int row = c0 + kg * 4 + j;
                if (row < count) {
                    float v = acc[j] + biasB;
                    v = v > 0.f ? v : expm1f(v);
                    h1[(size_t)(start + row) * 256 + n0 + cg * 16 + ln] = f2bf(v);
                }
            }
        }
    }
}

// ---------- L2+final: h1(256) -> h2(128, LDS) -> out(12), tanh --------------
// grid (4,64); 16-row chunk per iteration; h2 XOR-swizzled in LDS. (R10-proven)
__global__ __launch_bounds__(256) void l2f_kernel(const unsigned short* __restrict__ h1,
                                                  const int* __restrict__ offsets_g,
                                                  const int* __restrict__ order_g,
                                                  const float* __restrict__ w4,
                                                  const float* __restrict__ b4,
                                                  const float* __restrict__ w6,
                                                  const float* __restrict__ b6,
                                                  float* __restrict__ out) {
    __shared__ char h2b[4096];            // 16 rows x 128 cols bf16, swizzled
    const int t = blockIdx.y;
    const int start = offsets_g[t];
    const int count = offsets_g[t + 1] - start;
    if ((int)blockIdx.x * 16 >= count) return;
    const int lane = threadIdx.x & 63, wid = threadIdx.x >> 6;
    const int ln = lane & 15, kg = lane >> 4;
    const int nq = wid;

    short8 bfA[2][8];
    float biasA[2];
#pragma unroll
    for (int sub = 0; sub < 2; ++sub) {
        const float* wr = w4 + ((size_t)t * 128 + nq * 32 + sub * 16 + ln) * 256;
#pragma unroll
        for (int k8 = 0; k8 < 8; ++k8) {
            int kb = k8 * 32 + kg * 8;
            bfA[sub][k8] = cvt8(*(const float4*)(wr + kb), *(const float4*)(wr + kb + 4));
        }
        biasA[sub] = b4[(size_t)t * 128 + nq * 32 + sub * 16 + ln];
    }
    short8 bf6[4];
    float bias6 = 0.f;
    if (wid == 0) {
        const float* wr = w6 + ((size_t)t * 12 + (ln < 12 ? ln : 0)) * 128;
#pragma unroll
        for (int kt = 0; kt < 4; ++kt) {
            int kb = kt * 32 + kg * 8;
            bf6[kt] = cvt8(*(const float4*)(wr + kb), *(const float4*)(wr + kb + 4));
        }
        if (ln < 12) bias6 = b6[(size_t)t * 12 + ln];
    }

    for (int mt = blockIdx.x; mt * 16 < count; mt += gridDim.x) {
        const int gr0 = start + mt * 16;
        short8 af[8];
        const unsigned short* xr = h1 + (size_t)(gr0 + ln) * 256 + kg * 8;
#pragma unroll
        for (int k8 = 0; k8 < 8; ++k8) af[k8] = *(const short8*)(xr + k8 * 32);
#pragma unroll
        for (int sub = 0; sub < 2; ++sub) {
            f32x4 acc = {0.f, 0.f, 0.f, 0.f};
#pragma unroll
            for (int k8 = 0; k8 < 8; ++k8)
                acc = __builtin_amdgcn_mfma_f32_16x16x32_bf16(af[k8], bfA[sub][k8],
                                                              acc, 0, 0, 0);
            int col = nq * 32 + sub * 16 + ln;
#pragma unroll
            for (int j = 0; j < 4; ++j) {
                int row = kg * 4 + j;
                float v = acc[j] + biasA[sub];
                v = v > 0.f ? v : expm1f(v);
                int byte = (row * 256 + col * 2) ^ ((row & 7) << 4);
                *(unsigned short*)(h2b + byte) = f2bf(v);
            }
        }
        __syncthreads();
        if (wid == 0) {
            f32x4 acc = {0.f, 0.f, 0.f, 0.f};
#pragma unroll
            for (int kt = 0; kt < 4; ++kt) {
                int byte = (ln * 256 + (kt * 32 + kg * 8) * 2) ^ ((ln & 7) << 4);
                acc = __builtin_amdgcn_mfma_f32_16x16x32_bf16(
                    *(const short8*)(h2b + byte), bf6[kt], acc, 0, 0, 0);
            }
#pragma unroll
            for (int j = 0; j < 4; ++j) {
                int row = mt * 16 + kg * 4 + j;
                if (ln < 12 && row < count)
                    out[(size_t)order_g[start + row] * 12 + ln] = tanhf(acc[j] + bias6);
            }
        }
        __syncthreads();
    }
}

extern "C" void kernel_launch(void* const* d_in, const int* in_sizes, int n_in,
                              void* d_out, int out_size, void* d_ws, size_t ws_size,
                              hipStream_t stream) {
    const float* obs = (const float*)d_in[0];
    const int* tidx  = (const int*)d_in[1];
    const float* w0  = (const float*)d_in[2];
    const float* b0  = (const float*)d_in[3];
    const float* w2  = (const float*)d_in[4];
    const float* b2  = (const float*)d_in[5];
    const float* w4  = (const float*)d_in[6];
    const float* b4  = (const float*)d_in[7];
    const float* w6  = (const float*)d_in[8];
    const float* b6  = (const float*)d_in[9];
    float* out = (float*)d_out;

    // ws: offsets (65 ints) | order (2048 ints) | h1. bf16 activations in
    // sorted space; +16 rows slack so tail A-fragment overreads stay in-bounds
    // (slack rows hold finite 0xAA poison, their D rows are never stored).
    const int ROWS = BATCH + 16;
    char* ws = (char*)d_ws;
    int* offsets = (int*)ws;                              // 65 ints
    int* order   = (int*)(ws + 1024);                     // 2048 ints
    unsigned short* h1 = (unsigned short*)(ws + 16384);   // ROWS*256

    k01_kernel<<<dim3(8, NTEACH), 512, 0, stream>>>(obs, tidx, w0, b0, w2, b2,
                                                    offsets, order, h1);
    l2f_kernel<<<dim3(4, NTEACH), 256, 0, stream>>>(h1, offsets, order,
                                                    w4, b4, w6, b6, out);
}